// Round 1
// baseline (1130.754 us; speedup 1.0000x reference)
//
#include <hip/hip_runtime.h>

#define LN_EPS 1e-5f

// ---------------- K1: degree -> dis, cfac ----------------
// dis[b,i]  = rsqrt(1 + valid_i * sum_j adj[b,i,j]*valid_j)
// cfac[b,i] = valid_i * dis[b,i]
__global__ __launch_bounds__(256) void k_deg(const float* __restrict__ adj,
                                             const int* __restrict__ pm,
                                             float* __restrict__ dis,
                                             float* __restrict__ cfac,
                                             int L) {
    int row = blockIdx.x;            // b*L + i
    int b = row / L;
    int i = row - b * L;
    const float* arow = adj + (size_t)row * L;
    const int* pmb = pm + (size_t)b * L;
    int t = threadIdx.x;
    float s = 0.f;
    for (int j = t; j < L; j += 256) {
        float v = (pmb[j] == 0) ? 1.f : 0.f;
        s += arow[j] * v;
    }
    #pragma unroll
    for (int off = 32; off; off >>= 1) s += __shfl_down(s, off);
    __shared__ float wsum[4];
    int wid = t >> 6, lane = t & 63;
    if (lane == 0) wsum[wid] = s;
    __syncthreads();
    if (t == 0) {
        float tot = wsum[0] + wsum[1] + wsum[2] + wsum[3];
        float validi = (pmb[i] == 0) ? 1.f : 0.f;
        float deg = 1.f + validi * tot;   // >= 1 always (self-loop)
        float d = rsqrtf(deg);
        dis[row] = d;
        cfac[row] = validi * d;
    }
}

// ---------------- K2: agg = ew * dis_i * (valid_i * sum_j adj_ij*cfac_j*x_j + dis_i*x_i) ----------------
// Block: 32 rows x full D (=512). 256 threads, each owns 2 columns.
__global__ __launch_bounds__(256) void k_agg(const float* __restrict__ adj,
                                             const float* __restrict__ x,
                                             const int* __restrict__ pm,
                                             const float* __restrict__ dis,
                                             const float* __restrict__ cfac,
                                             const float* __restrict__ ew,
                                             float* __restrict__ agg,
                                             int L, int D) {
    __shared__ float adjs[64][36];   // [jj][row], stride 36 floats (144B, 16B aligned)
    int nrb = L >> 5;                // row-blocks per batch
    int blk = blockIdx.x;
    int b = blk / nrb;
    int i0 = (blk - b * nrb) << 5;
    int t = threadIdx.x;
    int c0 = t << 1;                 // column pair

    const float* xb = x + (size_t)b * L * D;
    const float* adjb = adj + ((size_t)b * L + i0) * L;
    const float* cfb = cfac + (size_t)b * L;

    float2 acc[32];
    #pragma unroll
    for (int r = 0; r < 32; ++r) acc[r] = make_float2(0.f, 0.f);

    int si = t >> 3;                 // staging row 0..31
    int sj0 = (t & 7) * 8;           // staging j offset
    const float* srow = adjb + (size_t)si * L;

    for (int jc = 0; jc < L; jc += 64) {
        float4 v0 = *(const float4*)(srow + jc + sj0);
        float4 v1 = *(const float4*)(srow + jc + sj0 + 4);
        float4 c0v = *(const float4*)(cfb + jc + sj0);
        float4 c1v = *(const float4*)(cfb + jc + sj0 + 4);
        adjs[sj0 + 0][si] = v0.x * c0v.x;
        adjs[sj0 + 1][si] = v0.y * c0v.y;
        adjs[sj0 + 2][si] = v0.z * c0v.z;
        adjs[sj0 + 3][si] = v0.w * c0v.w;
        adjs[sj0 + 4][si] = v1.x * c1v.x;
        adjs[sj0 + 5][si] = v1.y * c1v.y;
        adjs[sj0 + 6][si] = v1.z * c1v.z;
        adjs[sj0 + 7][si] = v1.w * c1v.w;
        __syncthreads();
        const float* xrow = xb + (size_t)jc * D + c0;
        for (int jj = 0; jj < 64; ++jj) {
            float2 xv = *(const float2*)(xrow + (size_t)jj * D);
            #pragma unroll
            for (int r = 0; r < 32; ++r) {
                float a = adjs[jj][r];   // wave-broadcast, conflict-free
                acc[r].x = fmaf(a, xv.x, acc[r].x);
                acc[r].y = fmaf(a, xv.y, acc[r].y);
            }
        }
        __syncthreads();
    }

    float eww = ew[0];
    const int* pmb = pm + (size_t)b * L;
    #pragma unroll
    for (int r = 0; r < 32; ++r) {
        int i = i0 + r;
        float d_i = dis[(size_t)b * L + i];
        float validi = (pmb[i] == 0) ? 1.f : 0.f;
        float2 xv = *(const float2*)(xb + (size_t)i * D + c0);
        float2 o;
        o.x = eww * d_i * (validi * acc[r].x + d_i * xv.x);
        o.y = eww * d_i * (validi * acc[r].y + d_i * xv.y);
        *(float2*)(agg + ((size_t)b * L + i) * D + c0) = o;
    }
}

// ---------------- K2.5: transpose W -> Wt ----------------
__global__ void k_transpose(const float* __restrict__ W, float* __restrict__ Wt, int D) {
    __shared__ float tile[32][33];
    int bx = blockIdx.x * 32, by = blockIdx.y * 32;
    int tx = threadIdx.x, ty = threadIdx.y;  // (32,8)
    #pragma unroll
    for (int k = 0; k < 32; k += 8)
        tile[ty + k][tx] = W[(size_t)(by + ty + k) * D + bx + tx];
    __syncthreads();
    #pragma unroll
    for (int k = 0; k < 32; k += 8)
        Wt[(size_t)(bx + ty + k) * D + by + tx] = tile[tx][ty + k];
}

// ---------------- K3: h = x + relu(agg @ W^T + b) * D^-0.5 (in place over agg buffer) ----------------
// Block: 32 rows x full D. Stages its own agg tile to LDS, then overwrites same rows with h.
__global__ __launch_bounds__(256) void k_lin(const float* __restrict__ x,
                                             const float* __restrict__ Wt,
                                             const float* __restrict__ bias,
                                             float* __restrict__ h,   // holds agg on entry
                                             int D) {
    __shared__ float aggs[512][32];  // [d][row], 64KB; inner reads are broadcast
    int i0 = blockIdx.x << 5;        // flat row over B*L
    int t = threadIdx.x;
    int c0 = t << 1;

    int si = t >> 3;
    int sd0 = (t & 7) * 64;
    const float* srow = h + ((size_t)(i0 + si)) * D + sd0;
    #pragma unroll
    for (int k = 0; k < 64; k += 4) {
        float4 v = *(const float4*)(srow + k);
        aggs[sd0 + k + 0][si] = v.x;
        aggs[sd0 + k + 1][si] = v.y;
        aggs[sd0 + k + 2][si] = v.z;
        aggs[sd0 + k + 3][si] = v.w;
    }
    __syncthreads();

    float2 acc[32];
    #pragma unroll
    for (int r = 0; r < 32; ++r) acc[r] = make_float2(0.f, 0.f);

    const float* wrow = Wt + c0;
    for (int d = 0; d < 512; ++d) {
        float2 wv = *(const float2*)(wrow + (size_t)d * D);
        #pragma unroll
        for (int r = 0; r < 32; ++r) {
            float a = aggs[d][r];    // broadcast
            acc[r].x = fmaf(a, wv.x, acc[r].x);
            acc[r].y = fmaf(a, wv.y, acc[r].y);
        }
    }

    float scale = 1.0f / sqrtf((float)D);
    float2 bv = *(const float2*)(bias + c0);
    #pragma unroll
    for (int r = 0; r < 32; ++r) {
        size_t row = (size_t)(i0 + r);
        float l0 = fmaxf(acc[r].x + bv.x, 0.f) * scale;
        float l1 = fmaxf(acc[r].y + bv.y, 0.f) * scale;
        float2 xv = *(const float2*)(x + row * D + c0);
        float2 o;
        o.x = xv.x + l0;
        o.y = xv.y + l1;
        *(float2*)(h + row * D + c0) = o;
    }
}

// ---------------- K4: LayerNorm in place ----------------
__global__ __launch_bounds__(256) void k_ln(float* __restrict__ h,
                                            const float* __restrict__ lnw,
                                            const float* __restrict__ lnb,
                                            int D) {
    size_t row = blockIdx.x;
    float* hr = h + row * D;
    int t = threadIdx.x;
    float2 v = *(const float2*)(hr + 2 * t);
    float s = v.x + v.y;
    float sq = v.x * v.x + v.y * v.y;
    #pragma unroll
    for (int off = 32; off; off >>= 1) {
        s += __shfl_down(s, off);
        sq += __shfl_down(sq, off);
    }
    __shared__ float ps[4], pq[4];
    int wid = t >> 6, lane = t & 63;
    if (lane == 0) { ps[wid] = s; pq[wid] = sq; }
    __syncthreads();
    float tot = ps[0] + ps[1] + ps[2] + ps[3];
    float totq = pq[0] + pq[1] + pq[2] + pq[3];
    float mu = tot / (float)D;
    float var = totq / (float)D - mu * mu;
    float rstd = rsqrtf(var + LN_EPS);
    float2 wv = *(const float2*)(lnw + 2 * t);
    float2 bv = *(const float2*)(lnb + 2 * t);
    float2 o;
    o.x = wv.x * (v.x - mu) * rstd + bv.x;
    o.y = wv.y * (v.y - mu) * rstd + bv.y;
    *(float2*)(hr + 2 * t) = o;
}

extern "C" void kernel_launch(void* const* d_in, const int* in_sizes, int n_in,
                              void* d_out, int out_size, void* d_ws, size_t ws_size,
                              hipStream_t stream) {
    const float* x    = (const float*)d_in[0];
    const float* adj  = (const float*)d_in[1];
    const int*   pm   = (const int*)d_in[2];
    const float* W    = (const float*)d_in[3];
    const float* bias = (const float*)d_in[4];
    const float* lnw  = (const float*)d_in[5];
    const float* lnb  = (const float*)d_in[6];
    const float* ew   = (const float*)d_in[7];

    int BL = in_sizes[2];                 // B*L
    int L  = in_sizes[1] / BL;            // (B*L*L)/(B*L)
    int B  = BL / L;
    int D  = in_sizes[0] / BL;

    float* out  = (float*)d_out;          // reused as agg scratch, then h, then final
    float* dis  = (float*)d_ws;
    float* cfac = dis + BL;
    float* Wt   = cfac + BL;

    k_deg<<<BL, 256, 0, stream>>>(adj, pm, dis, cfac, L);
    k_transpose<<<dim3(D / 32, D / 32), dim3(32, 8), 0, stream>>>(W, Wt, D);
    k_agg<<<B * (L / 32), 256, 0, stream>>>(adj, x, pm, dis, cfac, ew, out, L, D);
    k_lin<<<BL / 32, 256, 0, stream>>>(x, Wt, bias, out, D);
    k_ln<<<BL, 256, 0, stream>>>(out, lnw, lnb, D);
}

// Round 2
// 129.590 us; speedup vs baseline: 8.7256x; 8.7256x over previous
//
#include <hip/hip_runtime.h>

#define LN_EPS 1e-5f

typedef __attribute__((ext_vector_type(8))) short s16x8;
typedef __attribute__((ext_vector_type(4))) float f32x4;

__device__ inline unsigned int pk_bf16(float a, float b) {
    unsigned ua = __builtin_bit_cast(unsigned, a);
    unsigned ub = __builtin_bit_cast(unsigned, b);
    ua += 0x7fffu + ((ua >> 16) & 1u);
    ub += 0x7fffu + ((ub >> 16) & 1u);
    return (ua >> 16) | (ub & 0xffff0000u);
}
__device__ inline unsigned short cv_bf16(float a) {
    unsigned ua = __builtin_bit_cast(unsigned, a);
    ua += 0x7fffu + ((ua >> 16) & 1u);
    return (unsigned short)(ua >> 16);
}

// ---------------- K1: degree -> cfac, rs, rself ----------------
__global__ __launch_bounds__(256) void k_deg(const float* __restrict__ adj,
                                             const int* __restrict__ pm,
                                             const float* __restrict__ ew,
                                             float* __restrict__ cfac,
                                             float* __restrict__ rs,
                                             float* __restrict__ rself,
                                             int L) {
    int row = blockIdx.x;
    int b = row / L;
    int i = row - b * L;
    const float* arow = adj + (size_t)row * L;
    const int* pmb = pm + (size_t)b * L;
    int t = threadIdx.x;
    float s = 0.f;
    for (int j0 = t * 4; j0 < L; j0 += 1024) {
        float4 a = *(const float4*)(arow + j0);
        int4 p = *(const int4*)(pmb + j0);
        s += (p.x == 0 ? a.x : 0.f) + (p.y == 0 ? a.y : 0.f)
           + (p.z == 0 ? a.z : 0.f) + (p.w == 0 ? a.w : 0.f);
    }
    #pragma unroll
    for (int off = 32; off; off >>= 1) s += __shfl_down(s, off);
    __shared__ float wsum[4];
    if ((t & 63) == 0) wsum[t >> 6] = s;
    __syncthreads();
    if (t == 0) {
        float tot = wsum[0] + wsum[1] + wsum[2] + wsum[3];
        float validi = (pmb[i] == 0) ? 1.f : 0.f;
        float deg = 1.f + validi * tot;   // >= 1 (self-loop)
        float d = rsqrtf(deg);
        float e = ew[0];
        cfac[row]  = validi * d;
        rs[row]    = e * validi * d;
        rself[row] = e * d * d;
    }
}

// ---------------- K2: transpose + convert x -> xht[b, d, l] (bf16) ----------------
__global__ __launch_bounds__(256) void k_xt(const float* __restrict__ x,
                                            unsigned short* __restrict__ xht,
                                            int L, int D) {
    __shared__ float tile[64][65];
    int l0 = blockIdx.x << 6, d0 = blockIdx.y << 6, b = blockIdx.z;
    int t = threadIdx.x;
    int lr = t >> 2, c4 = (t & 3) << 4;
    const float* xp = x + ((size_t)b * L + l0 + lr) * D + d0 + c4;
    #pragma unroll
    for (int k = 0; k < 16; k += 4) {
        float4 v = *(const float4*)(xp + k);
        tile[lr][c4 + k + 0] = v.x;
        tile[lr][c4 + k + 1] = v.y;
        tile[lr][c4 + k + 2] = v.z;
        tile[lr][c4 + k + 3] = v.w;
    }
    __syncthreads();
    int dr = t >> 2, k0 = (t & 3) << 4;
    unsigned short* op = xht + ((size_t)b * D + d0 + dr) * L + l0 + k0;
    uint4 o0, o1;
    o0.x = pk_bf16(tile[k0 + 0][dr],  tile[k0 + 1][dr]);
    o0.y = pk_bf16(tile[k0 + 2][dr],  tile[k0 + 3][dr]);
    o0.z = pk_bf16(tile[k0 + 4][dr],  tile[k0 + 5][dr]);
    o0.w = pk_bf16(tile[k0 + 6][dr],  tile[k0 + 7][dr]);
    o1.x = pk_bf16(tile[k0 + 8][dr],  tile[k0 + 9][dr]);
    o1.y = pk_bf16(tile[k0 + 10][dr], tile[k0 + 11][dr]);
    o1.z = pk_bf16(tile[k0 + 12][dr], tile[k0 + 13][dr]);
    o1.w = pk_bf16(tile[k0 + 14][dr], tile[k0 + 15][dr]);
    *(uint4*)(op) = o0;
    *(uint4*)(op + 8) = o1;
}

// ---------------- K2b: convert W (already n-major, k-contiguous) -> bf16 ----------------
__global__ __launch_bounds__(256) void k_wh(const float* __restrict__ W,
                                            unsigned short* __restrict__ Wh) {
    int i = (blockIdx.x * 256 + threadIdx.x) * 4;
    float4 v = *(const float4*)(W + i);
    uint2 o;
    o.x = pk_bf16(v.x, v.y);
    o.y = pk_bf16(v.z, v.w);
    *(uint2*)(Wh + i) = o;
}

// ---------------- K3: agg = rs_i * (A_hat @ x) + rself_i * x  (MFMA bf16) ----------------
// C[M=2048,N=512] per batch; BM=BN=128, BK=64; 4 waves, each 64x64.
__global__ __launch_bounds__(256, 2) void k_aggmm(
    const float* __restrict__ adj,
    const unsigned short* __restrict__ xht,
    const float* __restrict__ x,
    const float* __restrict__ cfac,
    const float* __restrict__ rs,
    const float* __restrict__ rself,
    unsigned short* __restrict__ aggh,
    int L, int D)
{
    __shared__ __align__(16) unsigned short As[128 * 64];
    __shared__ __align__(16) unsigned short Bs[128 * 64];
    int bid = blockIdx.x;
    int wid = (bid & 7) * 64 + (bid >> 3);   // one batch per XCD
    int b   = wid >> 6;
    int t6  = wid & 63;
    int brow = (t6 >> 2) << 7;
    int bcol = (t6 & 3) << 7;

    int t = threadIdx.x;
    int lane = t & 63;
    int w = t >> 6;
    int wr = ((w >> 1) & 1) << 6;
    int wc = (w & 1) << 6;

    const float* adjb = adj + ((size_t)b * L + brow) * L;
    const unsigned short* xb = xht + ((size_t)b * D + bcol) * L;
    const float* cfb = cfac + (size_t)b * L;

    int sr8 = t >> 3;          // 0..31
    int chunk = t & 7;         // 16B chunk within 128B row
    int sw8 = (sr8 & 7) << 4;
    char* Ac = (char*)As;
    char* Bc = (char*)Bs;

    f32x4 acc[4][4];
    #pragma unroll
    for (int i = 0; i < 4; ++i)
        #pragma unroll
        for (int j = 0; j < 4; ++j)
            acc[i][j] = (f32x4){0.f, 0.f, 0.f, 0.f};

    const int lane15 = lane & 15;
    const int kbyte = (lane >> 4) << 4;
    const int swa = (lane & 7) << 4;

    for (int kc = 0; kc < L; kc += 64) {
        // cfac slice for this thread's chunk (reused across 4 rows)
        float4 cf0 = *(const float4*)(cfb + kc + chunk * 8);
        float4 cf1 = *(const float4*)(cfb + kc + chunk * 8 + 4);
        #pragma unroll
        for (int c = 0; c < 4; ++c) {
            int row = sr8 + (c << 5);
            const float* ap = adjb + (size_t)row * L + kc + chunk * 8;
            float4 a0 = *(const float4*)(ap);
            float4 a1 = *(const float4*)(ap + 4);
            uint4 o;
            o.x = pk_bf16(a0.x * cf0.x, a0.y * cf0.y);
            o.y = pk_bf16(a0.z * cf0.z, a0.w * cf0.w);
            o.z = pk_bf16(a1.x * cf1.x, a1.y * cf1.y);
            o.w = pk_bf16(a1.z * cf1.z, a1.w * cf1.w);
            *(uint4*)(Ac + row * 128 + ((chunk * 16) ^ sw8)) = o;
            const unsigned short* bp = xb + (size_t)row * L + kc + chunk * 8;
            *(uint4*)(Bc + row * 128 + ((chunk * 16) ^ sw8)) = *(const uint4*)(bp);
        }
        __syncthreads();
        #pragma unroll
        for (int kk = 0; kk < 2; ++kk) {
            s16x8 af[4], bg[4];
            #pragma unroll
            for (int f = 0; f < 4; ++f) {
                int ar = wr + (f << 4) + lane15;
                af[f] = *(const s16x8*)(Ac + ar * 128 + (((kk << 6) + kbyte) ^ swa));
                int br = wc + (f << 4) + lane15;
                bg[f] = *(const s16x8*)(Bc + br * 128 + (((kk << 6) + kbyte) ^ swa));
            }
            #pragma unroll
            for (int fm = 0; fm < 4; ++fm)
                #pragma unroll
                for (int fn = 0; fn < 4; ++fn)
                    acc[fm][fn] = __builtin_amdgcn_mfma_f32_16x16x32_bf16(af[fm], bg[fn], acc[fm][fn], 0, 0, 0);
        }
        __syncthreads();
    }

    int col = lane15;
    int r0 = (lane >> 4) << 2;
    size_t bL = (size_t)b * L;
    #pragma unroll
    for (int fm = 0; fm < 4; ++fm) {
        #pragma unroll
        for (int j = 0; j < 4; ++j) {
            int gi = brow + wr + (fm << 4) + r0 + j;
            float rsi = rs[bL + gi];
            float rfi = rself[bL + gi];
            const float* xrow = x + (bL + gi) * (size_t)D;
            unsigned short* orow = aggh + (bL + gi) * (size_t)D;
            #pragma unroll
            for (int fn = 0; fn < 4; ++fn) {
                int gd = bcol + wc + (fn << 4) + col;
                float v = rsi * acc[fm][fn][j] + rfi * xrow[gd];
                orow[gd] = cv_bf16(v);
            }
        }
    }
}

// ---------------- K4: h = x + relu(agg @ W^T + b) * D^-0.5  (MFMA bf16) ----------------
__global__ __launch_bounds__(256, 2) void k_lin(
    const unsigned short* __restrict__ aggh,
    const unsigned short* __restrict__ Wh,
    const float* __restrict__ bias,
    const float* __restrict__ x,
    float* __restrict__ out,
    int D)
{
    __shared__ __align__(16) unsigned short As[128 * 64];
    __shared__ __align__(16) unsigned short Bs[128 * 64];
    int bid = blockIdx.x;
    int brow = (bid >> 2) << 7;
    int bcol = (bid & 3) << 7;

    int t = threadIdx.x;
    int lane = t & 63;
    int w = t >> 6;
    int wr = ((w >> 1) & 1) << 6;
    int wc = (w & 1) << 6;

    int sr8 = t >> 3;
    int chunk = t & 7;
    int sw8 = (sr8 & 7) << 4;
    char* Ac = (char*)As;
    char* Bc = (char*)Bs;

    f32x4 acc[4][4];
    #pragma unroll
    for (int i = 0; i < 4; ++i)
        #pragma unroll
        for (int j = 0; j < 4; ++j)
            acc[i][j] = (f32x4){0.f, 0.f, 0.f, 0.f};

    const int lane15 = lane & 15;
    const int kbyte = (lane >> 4) << 4;
    const int swa = (lane & 7) << 4;

    for (int kc = 0; kc < D; kc += 64) {
        #pragma unroll
        for (int c = 0; c < 4; ++c) {
            int row = sr8 + (c << 5);
            const unsigned short* ap = aggh + (size_t)(brow + row) * D + kc + chunk * 8;
            *(uint4*)(Ac + row * 128 + ((chunk * 16) ^ sw8)) = *(const uint4*)(ap);
            const unsigned short* bp = Wh + (size_t)(bcol + row) * D + kc + chunk * 8;
            *(uint4*)(Bc + row * 128 + ((chunk * 16) ^ sw8)) = *(const uint4*)(bp);
        }
        __syncthreads();
        #pragma unroll
        for (int kk = 0; kk < 2; ++kk) {
            s16x8 af[4], bg[4];
            #pragma unroll
            for (int f = 0; f < 4; ++f) {
                int ar = wr + (f << 4) + lane15;
                af[f] = *(const s16x8*)(Ac + ar * 128 + (((kk << 6) + kbyte) ^ swa));
                int br = wc + (f << 4) + lane15;
                bg[f] = *(const s16x8*)(Bc + br * 128 + (((kk << 6) + kbyte) ^ swa));
            }
            #pragma unroll
            for (int fm = 0; fm < 4; ++fm)
                #pragma unroll
                for (int fn = 0; fn < 4; ++fn)
                    acc[fm][fn] = __builtin_amdgcn_mfma_f32_16x16x32_bf16(af[fm], bg[fn], acc[fm][fn], 0, 0, 0);
        }
        __syncthreads();
    }

    float scale = 1.0f / sqrtf((float)D);
    int col = lane15;
    int r0 = (lane >> 4) << 2;
    #pragma unroll
    for (int fm = 0; fm < 4; ++fm) {
        #pragma unroll
        for (int j = 0; j < 4; ++j) {
            int gi = brow + wr + (fm << 4) + r0 + j;
            const float* xrow = x + (size_t)gi * D;
            float* orow = out + (size_t)gi * D;
            #pragma unroll
            for (int fn = 0; fn < 4; ++fn) {
                int gd = bcol + wc + (fn << 4) + col;
                float v = acc[fm][fn][j] + bias[gd];
                orow[gd] = fmaxf(v, 0.f) * scale + xrow[gd];
            }
        }
    }
}

// ---------------- K5: LayerNorm in place ----------------
__global__ __launch_bounds__(256) void k_ln(float* __restrict__ h,
                                            const float* __restrict__ lnw,
                                            const float* __restrict__ lnb,
                                            int D) {
    size_t row = blockIdx.x;
    float* hr = h + row * D;
    int t = threadIdx.x;
    float2 v = *(const float2*)(hr + 2 * t);
    float s = v.x + v.y;
    float sq = v.x * v.x + v.y * v.y;
    #pragma unroll
    for (int off = 32; off; off >>= 1) {
        s += __shfl_down(s, off);
        sq += __shfl_down(sq, off);
    }
    __shared__ float ps[4], pq[4];
    int wid = t >> 6, lane = t & 63;
    if (lane == 0) { ps[wid] = s; pq[wid] = sq; }
    __syncthreads();
    float tot = ps[0] + ps[1] + ps[2] + ps[3];
    float totq = pq[0] + pq[1] + pq[2] + pq[3];
    float mu = tot / (float)D;
    float var = totq / (float)D - mu * mu;
    float rstd = rsqrtf(var + LN_EPS);
    float2 wv = *(const float2*)(lnw + 2 * t);
    float2 bv = *(const float2*)(lnb + 2 * t);
    float2 o;
    o.x = wv.x * (v.x - mu) * rstd + bv.x;
    o.y = wv.y * (v.y - mu) * rstd + bv.y;
    *(float2*)(hr + 2 * t) = o;
}

extern "C" void kernel_launch(void* const* d_in, const int* in_sizes, int n_in,
                              void* d_out, int out_size, void* d_ws, size_t ws_size,
                              hipStream_t stream) {
    const float* x    = (const float*)d_in[0];
    const float* adj  = (const float*)d_in[1];
    const int*   pm   = (const int*)d_in[2];
    const float* W    = (const float*)d_in[3];
    const float* bias = (const float*)d_in[4];
    const float* lnw  = (const float*)d_in[5];
    const float* lnb  = (const float*)d_in[6];
    const float* ew   = (const float*)d_in[7];

    int BL = in_sizes[2];                 // B*L = 16384
    int L  = in_sizes[1] / BL;            // 2048
    int B  = BL / L;                      // 8
    int D  = in_sizes[0] / BL;            // 512

    char* ws = (char*)d_ws;
    float* cfac  = (float*)(ws);
    float* rs    = (float*)(ws + (size_t)BL * 4);
    float* rself = (float*)(ws + (size_t)BL * 8);
    unsigned short* xht  = (unsigned short*)(ws + (size_t)BL * 12);
    unsigned short* Wh   = (unsigned short*)(ws + (size_t)BL * 12 + (size_t)B * D * L * 2);
    unsigned short* aggh = (unsigned short*)(ws + (size_t)BL * 12 + (size_t)B * D * L * 2 + (size_t)D * D * 2);

    float* out = (float*)d_out;

    k_deg<<<BL, 256, 0, stream>>>(adj, pm, ew, cfac, rs, rself, L);
    k_wh<<<(D * D) / 1024, 256, 0, stream>>>(W, Wh);
    k_xt<<<dim3(L / 64, D / 64, B), 256, 0, stream>>>(x, xht, L, D);
    k_aggmm<<<B * (L / 128) * (D / 128), 256, 0, stream>>>(adj, xht, x, cfac, rs, rself, aggh, L, D);
    k_lin<<<(BL / 128) * (D / 128), 256, 0, stream>>>(aggh, Wh, bias, x, out, D);
    k_ln<<<BL, 256, 0, stream>>>(out, lnw, lnb, D);
}

// Round 3
// 113.645 us; speedup vs baseline: 9.9498x; 1.1403x over previous
//
#include <hip/hip_runtime.h>

#define LN_EPS 1e-5f

typedef __attribute__((ext_vector_type(8))) short s16x8;
typedef __attribute__((ext_vector_type(4))) float f32x4;

__device__ inline unsigned int pk_bf16(float a, float b) {
    unsigned ua = __builtin_bit_cast(unsigned, a);
    unsigned ub = __builtin_bit_cast(unsigned, b);
    ua += 0x7fffu + ((ua >> 16) & 1u);
    ub += 0x7fffu + ((ub >> 16) & 1u);
    return (ua >> 16) | (ub & 0xffff0000u);
}

__device__ inline void gl_lds16(const void* g, void* l) {
    __builtin_amdgcn_global_load_lds((const __attribute__((address_space(1))) void*)g,
                                     (__attribute__((address_space(3))) void*)l, 16, 0, 0);
}

// ---------------- K1: degree pass + masked bf16 adjacency ----------------
// am[b,i,j] = bf16(adj * valid_i * valid_j); dis = rsqrt(1 + valid_i*rowsum)
__global__ __launch_bounds__(256) void k_deg(const float* __restrict__ adj,
                                             const int* __restrict__ pm,
                                             const float* __restrict__ ew,
                                             float* __restrict__ dis_o,
                                             float* __restrict__ rs,
                                             float* __restrict__ rself,
                                             unsigned short* __restrict__ am,
                                             int L) {
    int row = blockIdx.x;
    int b = row / L;
    int i = row - b * L;
    const float* arow = adj + (size_t)row * L;
    const int* pmb = pm + (size_t)b * L;
    unsigned short* amrow = am + (size_t)row * L;
    int t = threadIdx.x;
    float validi = (pmb[i] == 0) ? 1.f : 0.f;
    float s = 0.f;
    for (int j0 = t * 8; j0 < L; j0 += 2048) {
        float4 a0 = *(const float4*)(arow + j0);
        float4 a1 = *(const float4*)(arow + j0 + 4);
        int4 p0 = *(const int4*)(pmb + j0);
        int4 p1 = *(const int4*)(pmb + j0 + 4);
        float m0 = p0.x == 0 ? a0.x : 0.f;
        float m1 = p0.y == 0 ? a0.y : 0.f;
        float m2 = p0.z == 0 ? a0.z : 0.f;
        float m3 = p0.w == 0 ? a0.w : 0.f;
        float m4 = p1.x == 0 ? a1.x : 0.f;
        float m5 = p1.y == 0 ? a1.y : 0.f;
        float m6 = p1.z == 0 ? a1.z : 0.f;
        float m7 = p1.w == 0 ? a1.w : 0.f;
        s += ((m0 + m1) + (m2 + m3)) + ((m4 + m5) + (m6 + m7));
        uint4 o;
        o.x = pk_bf16(validi * m0, validi * m1);
        o.y = pk_bf16(validi * m2, validi * m3);
        o.z = pk_bf16(validi * m4, validi * m5);
        o.w = pk_bf16(validi * m6, validi * m7);
        *(uint4*)(amrow + j0) = o;
    }
    #pragma unroll
    for (int off = 32; off; off >>= 1) s += __shfl_down(s, off);
    __shared__ float wsum[4];
    if ((t & 63) == 0) wsum[t >> 6] = s;
    __syncthreads();
    if (t == 0) {
        float tot = wsum[0] + wsum[1] + wsum[2] + wsum[3];
        float deg = 1.f + validi * tot;   // >= 1 (self-loop)
        float d = rsqrtf(deg);
        float e = ew[0];
        dis_o[row]  = d;
        rs[row]     = e * validi * d;
        rself[row]  = e * d * d;
    }
}

// ---------------- K2: transpose + scale + convert: yht[b,d,l] = bf16(dis_l * x[b,l,d]) ----------------
__global__ __launch_bounds__(256) void k_xt(const float* __restrict__ x,
                                            const float* __restrict__ dis,
                                            unsigned short* __restrict__ yht,
                                            int L, int D) {
    __shared__ float tile[64][65];
    int l0 = blockIdx.x << 6, d0 = blockIdx.y << 6, b = blockIdx.z;
    int t = threadIdx.x;
    int lr = t >> 2, c4 = (t & 3) << 4;
    float dl = dis[(size_t)b * L + l0 + lr];
    const float* xp = x + ((size_t)b * L + l0 + lr) * D + d0 + c4;
    #pragma unroll
    for (int k = 0; k < 16; k += 4) {
        float4 v = *(const float4*)(xp + k);
        tile[lr][c4 + k + 0] = v.x * dl;
        tile[lr][c4 + k + 1] = v.y * dl;
        tile[lr][c4 + k + 2] = v.z * dl;
        tile[lr][c4 + k + 3] = v.w * dl;
    }
    __syncthreads();
    int dr = t >> 2, k0 = (t & 3) << 4;
    unsigned short* op = yht + ((size_t)b * D + d0 + dr) * L + l0 + k0;
    uint4 o0, o1;
    o0.x = pk_bf16(tile[k0 + 0][dr],  tile[k0 + 1][dr]);
    o0.y = pk_bf16(tile[k0 + 2][dr],  tile[k0 + 3][dr]);
    o0.z = pk_bf16(tile[k0 + 4][dr],  tile[k0 + 5][dr]);
    o0.w = pk_bf16(tile[k0 + 6][dr],  tile[k0 + 7][dr]);
    o1.x = pk_bf16(tile[k0 + 8][dr],  tile[k0 + 9][dr]);
    o1.y = pk_bf16(tile[k0 + 10][dr], tile[k0 + 11][dr]);
    o1.z = pk_bf16(tile[k0 + 12][dr], tile[k0 + 13][dr]);
    o1.w = pk_bf16(tile[k0 + 14][dr], tile[k0 + 15][dr]);
    *(uint4*)(op) = o0;
    *(uint4*)(op + 8) = o1;
}

// ---------------- K2b: W -> bf16 ----------------
__global__ __launch_bounds__(256) void k_wh(const float* __restrict__ W,
                                            unsigned short* __restrict__ Wh) {
    int i = (blockIdx.x * 256 + threadIdx.x) * 4;
    float4 v = *(const float4*)(W + i);
    uint2 o;
    o.x = pk_bf16(v.x, v.y);
    o.y = pk_bf16(v.z, v.w);
    *(uint2*)(Wh + i) = o;
}

// ---------------- K3: agg = rs_i * (am @ y) + rself_i * x  (MFMA bf16, direct LDS staging) ----------------
// BM=BN=128, BK=64; 4 waves of 64x64.
__global__ __launch_bounds__(256, 2) void k_aggmm(
    const unsigned short* __restrict__ am,
    const unsigned short* __restrict__ yht,
    const float* __restrict__ x,
    const float* __restrict__ rs,
    const float* __restrict__ rself,
    unsigned short* __restrict__ aggh,
    int L, int D)
{
    __shared__ __align__(16) unsigned short As[128 * 64];
    __shared__ __align__(16) unsigned short Bs[128 * 64];
    int bid = blockIdx.x;
    int wid = (bid & 7) * 64 + (bid >> 3);   // one batch per XCD (512 = 8*64, bijective)
    int b   = wid >> 6;
    int t6  = wid & 63;
    int brow = (t6 >> 2) << 7;
    int bcol = (t6 & 3) << 7;

    int t = threadIdx.x;
    int lane = t & 63;
    int w = t >> 6;
    int wr = ((w >> 1) & 1) << 6;
    int wc = (w & 1) << 6;

    const unsigned short* amb = am + ((size_t)b * L + brow) * L;
    const unsigned short* yb  = yht + ((size_t)b * D + bcol) * L;

    int srow = t >> 3;          // 0..31
    int chunk = t & 7;
    char* Ac = (char*)As;
    char* Bc = (char*)Bs;

    f32x4 acc[4][4];
    #pragma unroll
    for (int i = 0; i < 4; ++i)
        #pragma unroll
        for (int j = 0; j < 4; ++j)
            acc[i][j] = (f32x4){0.f, 0.f, 0.f, 0.f};

    const int lane15 = lane & 15;
    const int kbyte = (lane >> 4) << 4;
    const int swa = (lane & 7) << 4;

    for (int kc = 0; kc < L; kc += 64) {
        #pragma unroll
        for (int q = 0; q < 4; ++q) {
            int row = srow + (q << 5);
            int sc = chunk ^ (row & 7);      // pre-swizzled global source, linear LDS dest
            gl_lds16(amb + (size_t)row * L + kc + sc * 8, Ac + row * 128 + chunk * 16);
            gl_lds16(yb  + (size_t)row * L + kc + sc * 8, Bc + row * 128 + chunk * 16);
        }
        asm volatile("s_waitcnt vmcnt(0)" ::: "memory");
        __syncthreads();
        #pragma unroll
        for (int kk = 0; kk < 2; ++kk) {
            s16x8 af[4], bg[4];
            #pragma unroll
            for (int f = 0; f < 4; ++f) {
                int ar = wr + (f << 4) + lane15;
                af[f] = *(const s16x8*)(Ac + ar * 128 + (((kk << 6) + kbyte) ^ swa));
                int br = wc + (f << 4) + lane15;
                bg[f] = *(const s16x8*)(Bc + br * 128 + (((kk << 6) + kbyte) ^ swa));
            }
            #pragma unroll
            for (int fm = 0; fm < 4; ++fm)
                #pragma unroll
                for (int fn = 0; fn < 4; ++fn)
                    acc[fm][fn] = __builtin_amdgcn_mfma_f32_16x16x32_bf16(af[fm], bg[fn], acc[fm][fn], 0, 0, 0);
        }
        __syncthreads();
    }

    int col = lane15;
    int r0 = (lane >> 4) << 2;
    size_t bL = (size_t)b * L;
    #pragma unroll
    for (int fm = 0; fm < 4; ++fm) {
        #pragma unroll
        for (int j = 0; j < 4; ++j) {
            int gi = brow + wr + (fm << 4) + r0 + j;
            float rsi = rs[bL + gi];
            float rfi = rself[bL + gi];
            const float* xrow = x + (bL + gi) * (size_t)D;
            unsigned short* orow = aggh + (bL + gi) * (size_t)D;
            #pragma unroll
            for (int fn = 0; fn < 4; ++fn) {
                int gd = bcol + wc + (fn << 4) + col;
                float v = rsi * acc[fm][fn][j] + rfi * xrow[gd];
                unsigned ua = __builtin_bit_cast(unsigned, v);
                ua += 0x7fffu + ((ua >> 16) & 1u);
                orow[gd] = (unsigned short)(ua >> 16);
            }
        }
    }
}

// ---------------- K4: out = LN(x + relu(agg @ W^T + b) * D^-0.5)  (fused, BM=32 x BN=512) ----------------
__global__ __launch_bounds__(256, 2) void k_linln(
    const unsigned short* __restrict__ aggh,
    const unsigned short* __restrict__ Wh,
    const float* __restrict__ bias,
    const float* __restrict__ x,
    const float* __restrict__ lnw,
    const float* __restrict__ lnb,
    float* __restrict__ out)
{
    const int D = 512;
    __shared__ __align__(16) unsigned short As[32 * 64];    // 4KB
    __shared__ __align__(16) unsigned short Bs[512 * 64];   // 64KB
    __shared__ float psum[32][4], psq[32][4];

    int i0 = blockIdx.x << 5;
    int t = threadIdx.x;
    int lane = t & 63;
    int w = t >> 6;
    int wc = w << 7;                 // wave column base (0,128,256,384)

    int srow = t >> 3;               // 0..31
    int chunk = t & 7;
    char* Ac = (char*)As;
    char* Bc = (char*)Bs;

    f32x4 acc[2][8];
    #pragma unroll
    for (int i = 0; i < 2; ++i)
        #pragma unroll
        for (int j = 0; j < 8; ++j)
            acc[i][j] = (f32x4){0.f, 0.f, 0.f, 0.f};

    const int lane15 = lane & 15;
    const int kbyte = (lane >> 4) << 4;
    const int swa = (lane & 7) << 4;

    for (int kc = 0; kc < D; kc += 64) {
        {   // A: 32 rows of aggh
            int sc = chunk ^ (srow & 7);
            gl_lds16(aggh + (size_t)(i0 + srow) * D + kc + sc * 8, Ac + srow * 128 + chunk * 16);
        }
        #pragma unroll
        for (int q = 0; q < 16; ++q) {   // B: all 512 rows of Wh
            int row = srow + (q << 5);
            int sc = chunk ^ (row & 7);
            gl_lds16(Wh + (size_t)row * D + kc + sc * 8, Bc + row * 128 + chunk * 16);
        }
        asm volatile("s_waitcnt vmcnt(0)" ::: "memory");
        __syncthreads();
        #pragma unroll
        for (int kk = 0; kk < 2; ++kk) {
            s16x8 af[2], bg[8];
            #pragma unroll
            for (int f = 0; f < 2; ++f) {
                int ar = (f << 4) + lane15;
                af[f] = *(const s16x8*)(Ac + ar * 128 + (((kk << 6) + kbyte) ^ ((ar & 7) << 4)));
            }
            #pragma unroll
            for (int f = 0; f < 8; ++f) {
                int br = wc + (f << 4) + lane15;
                bg[f] = *(const s16x8*)(Bc + br * 128 + (((kk << 6) + kbyte) ^ swa));
            }
            #pragma unroll
            for (int fm = 0; fm < 2; ++fm)
                #pragma unroll
                for (int fn = 0; fn < 8; ++fn)
                    acc[fm][fn] = __builtin_amdgcn_mfma_f32_16x16x32_bf16(af[fm], bg[fn], acc[fm][fn], 0, 0, 0);
        }
        __syncthreads();
    }

    // epilogue: h = x + relu(acc + b)*scale, then LN over full rows
    const float scale = 0.044194173824159216f;   // 512^-0.5
    float bi[8], lw[8], lb[8];
    #pragma unroll
    for (int fn = 0; fn < 8; ++fn) {
        int colg = wc + (fn << 4) + lane15;
        bi[fn] = bias[colg];
        lw[fn] = lnw[colg];
        lb[fn] = lnb[colg];
    }
    int r0 = (lane >> 4) << 2;
    #pragma unroll
    for (int fm = 0; fm < 2; ++fm) {
        #pragma unroll
        for (int j = 0; j < 4; ++j) {
            int r = (fm << 4) + r0 + j;
            const float* xrow = x + (size_t)(i0 + r) * D;
            float s = 0.f, q = 0.f;
            #pragma unroll
            for (int fn = 0; fn < 8; ++fn) {
                int colg = wc + (fn << 4) + lane15;
                float v = fmaxf(acc[fm][fn][j] + bi[fn], 0.f) * scale + xrow[colg];
                acc[fm][fn][j] = v;
                s += v;
                q += v * v;
            }
            #pragma unroll
            for (int m = 1; m < 16; m <<= 1) {
                s += __shfl_xor(s, m);
                q += __shfl_xor(q, m);
            }
            if (lane15 == 0) { psum[r][w] = s; psq[r][w] = q; }
        }
    }
    __syncthreads();
    #pragma unroll
    for (int fm = 0; fm < 2; ++fm) {
        #pragma unroll
        for (int j = 0; j < 4; ++j) {
            int r = (fm << 4) + r0 + j;
            float s = psum[r][0] + psum[r][1] + psum[r][2] + psum[r][3];
            float q = psq[r][0] + psq[r][1] + psq[r][2] + psq[r][3];
            float mu = s * (1.f / 512.f);
            float var = q * (1.f / 512.f) - mu * mu;
            float rstd = rsqrtf(var + LN_EPS);
            float* orow = out + (size_t)(i0 + r) * D;
            #pragma unroll
            for (int fn = 0; fn < 8; ++fn) {
                int colg = wc + (fn << 4) + lane15;
                orow[colg] = lw[fn] * (acc[fm][fn][j] - mu) * rstd + lb[fn];
            }
        }
    }
}

extern "C" void kernel_launch(void* const* d_in, const int* in_sizes, int n_in,
                              void* d_out, int out_size, void* d_ws, size_t ws_size,
                              hipStream_t stream) {
    const float* x    = (const float*)d_in[0];
    const float* adj  = (const float*)d_in[1];
    const int*   pm   = (const int*)d_in[2];
    const float* W    = (const float*)d_in[3];
    const float* bias = (const float*)d_in[4];
    const float* lnw  = (const float*)d_in[5];
    const float* lnb  = (const float*)d_in[6];
    const float* ew   = (const float*)d_in[7];

    int BL = in_sizes[2];                 // B*L = 16384
    int L  = in_sizes[1] / BL;            // 2048
    int B  = BL / L;                      // 8
    int D  = in_sizes[0] / BL;            // 512

    char* ws = (char*)d_ws;
    size_t off = 0;
    float* dis   = (float*)(ws + off); off += (size_t)BL * 4;
    float* rs    = (float*)(ws + off); off += (size_t)BL * 4;
    float* rself = (float*)(ws + off); off += (size_t)BL * 4;
    unsigned short* am   = (unsigned short*)(ws + off); off += (size_t)BL * L * 2;
    unsigned short* yht  = (unsigned short*)(ws + off); off += (size_t)BL * D * 2;
    unsigned short* Wh   = (unsigned short*)(ws + off); off += (size_t)D * D * 2;
    unsigned short* aggh = (unsigned short*)(ws + off); off += (size_t)BL * D * 2;

    float* out = (float*)d_out;

    k_deg<<<BL, 256, 0, stream>>>(adj, pm, ew, dis, rs, rself, am, L);
    k_wh<<<(D * D) / 1024, 256, 0, stream>>>(W, Wh);
    k_xt<<<dim3(L / 64, D / 64, B), 256, 0, stream>>>(x, dis, yht, L, D);
    k_aggmm<<<B * (L / 128) * (D / 128), 256, 0, stream>>>(am, yht, x, rs, rself, aggh, L, D);
    k_linln<<<BL / 32, 256, 0, stream>>>(aggh, Wh, bias, x, lnw, lnb, out);
}